// Round 3
// baseline (4157.983 us; speedup 1.0000x reference)
//
#include <hip/hip_runtime.h>
#include <hip/hip_bf16.h>
#include <math.h>

typedef __hip_bfloat16 bf16_t;
typedef __bf16 bhalf8 __attribute__((ext_vector_type(8)));
typedef float f32x4 __attribute__((ext_vector_type(4)));

#define DEPTH 4
#define DIM   1024
#define ADIM  256
#define HID   4096
#define BATCH 4
#define SEQ   4096
#define MTOT  (BATCH*SEQ)   // 16384 rows
#define MCHUNK 4096         // MLP hidden computed in 4 row-chunks

// ---------------------------------------------------------------------------
// cast+transpose: W [K][N] fp32 -> WT [N][K] bf16  (B^T rows for the GEMM)
// grid (N/32, K/32), block (32,8)
// ---------------------------------------------------------------------------
__global__ __launch_bounds__(256) void cast_transpose(
    const float* __restrict__ W, bf16_t* __restrict__ WT, int K, int N)
{
    __shared__ float t[32][33];
    unsigned short* WTl = (unsigned short*)WT;
    int n0 = blockIdx.x * 32, k0 = blockIdx.y * 32;
    int tx = threadIdx.x, ty = threadIdx.y;
#pragma unroll
    for (int i = 0; i < 4; i++)
        t[ty + i * 8][tx] = W[(size_t)(k0 + ty + i * 8) * N + n0 + tx];
    __syncthreads();
#pragma unroll
    for (int i = 0; i < 4; i++) {
        __hip_bfloat16 v = __float2bfloat16(t[tx][ty + i * 8]);
        WTl[(size_t)(n0 + ty + i * 8) * K + k0 + tx] = *(unsigned short*)&v;
    }
}

// ---------------------------------------------------------------------------
// LayerNorm: x fp32 [M,1024] -> h bf16 [M,1024]. One block / row.
// ---------------------------------------------------------------------------
__global__ __launch_bounds__(256) void ln_kernel(
    const float* __restrict__ x, const float* __restrict__ g,
    const float* __restrict__ b, bf16_t* __restrict__ h)
{
    int row = blockIdx.x;
    const float* xr = x + (size_t)row * DIM;
    int tid = threadIdx.x;
    float4 v = ((const float4*)xr)[tid];
    float s  = v.x + v.y + v.z + v.w;
    float ss = v.x * v.x + v.y * v.y + v.z * v.z + v.w * v.w;
#pragma unroll
    for (int off = 32; off > 0; off >>= 1) {
        s  += __shfl_down(s, off, 64);
        ss += __shfl_down(ss, off, 64);
    }
    __shared__ float sbuf[8];
    int wid = tid >> 6, lane = tid & 63;
    if (lane == 0) { sbuf[wid] = s; sbuf[4 + wid] = ss; }
    __syncthreads();
    if (tid == 0) {
        float S  = sbuf[0] + sbuf[1] + sbuf[2] + sbuf[3];
        float SS = sbuf[4] + sbuf[5] + sbuf[6] + sbuf[7];
        float mu  = S * (1.f / DIM);
        float var = SS * (1.f / DIM) - mu * mu;
        sbuf[0] = mu;
        sbuf[1] = rsqrtf(var + 1e-6f);
    }
    __syncthreads();
    float mu = sbuf[0], rs = sbuf[1];
    bf16_t* hr = h + (size_t)row * DIM;
    int c = tid * 4;
    float4 gv = ((const float4*)g)[tid];
    float4 bv = ((const float4*)b)[tid];
    hr[c + 0] = __float2bfloat16((v.x - mu) * rs * gv.x + bv.x);
    hr[c + 1] = __float2bfloat16((v.y - mu) * rs * gv.y + bv.y);
    hr[c + 2] = __float2bfloat16((v.z - mu) * rs * gv.z + bv.z);
    hr[c + 3] = __float2bfloat16((v.w - mu) * rs * gv.w + bv.w);
}

// ---------------------------------------------------------------------------
// q/k l2-normalize (in-place fp32) + a = (qn . w_g)*SCALE, assq[b] += a^2
// block = 256 (4 waves, one row per wave), grid = M/4
// ---------------------------------------------------------------------------
__global__ __launch_bounds__(256) void qknorm(
    float* __restrict__ q, float* __restrict__ k,
    const float* __restrict__ wg, float* __restrict__ a,
    float* __restrict__ assq)
{
    int wid = threadIdx.x >> 6, lane = threadIdx.x & 63;
    int row = blockIdx.x * 4 + wid;
    float4* qr = (float4*)(q + (size_t)row * ADIM);
    float4* kr = (float4*)(k + (size_t)row * ADIM);
    float4 qv = qr[lane], kv = kr[lane];
    float qss = qv.x * qv.x + qv.y * qv.y + qv.z * qv.z + qv.w * qv.w;
    float kss = kv.x * kv.x + kv.y * kv.y + kv.z * kv.z + kv.w * kv.w;
#pragma unroll
    for (int off = 32; off > 0; off >>= 1) {
        qss += __shfl_down(qss, off, 64);
        kss += __shfl_down(kss, off, 64);
    }
    qss = __shfl(qss, 0, 64);
    kss = __shfl(kss, 0, 64);
    float qi = 1.f / fmaxf(sqrtf(qss), 1e-12f);
    float ki = 1.f / fmaxf(sqrtf(kss), 1e-12f);
    qv.x *= qi; qv.y *= qi; qv.z *= qi; qv.w *= qi;
    kv.x *= ki; kv.y *= ki; kv.z *= ki; kv.w *= ki;
    qr[lane] = qv;
    kr[lane] = kv;
    // a = dot(qn, w_g) * SCALE
    float4 wgv = ((const float4*)wg)[lane];
    float ad = qv.x * wgv.x + qv.y * wgv.y + qv.z * wgv.z + qv.w * wgv.w;
#pragma unroll
    for (int off = 32; off > 0; off >>= 1) ad += __shfl_down(ad, off, 64);
    if (lane == 0) {
        float av = ad * 0.25f;  // SCALE = 16^-0.5
        a[row] = av;
        atomicAdd(&assq[row >> 12], av * av);   // 4096 rows / batch
    }
}

// ---------------------------------------------------------------------------
// G_raw[b][d] = sum_n a[b,n] * qn[b,n,d]   (atomic accumulate, G pre-zeroed)
// grid (16 chunks, 4 batches), block 256 (d)
// ---------------------------------------------------------------------------
__global__ __launch_bounds__(256) void gacc(
    const float* __restrict__ q, const float* __restrict__ a,
    float* __restrict__ G)
{
    int b = blockIdx.y, chunk = blockIdx.x, d = threadIdx.x;
    const float* qb = q + ((size_t)b * SEQ + chunk * 256) * ADIM;
    const float* ab = a + (size_t)b * SEQ + chunk * 256;
    float s = 0.f;
    for (int n = 0; n < 256; n++) s += ab[n] * qb[(size_t)n * ADIM + d];
    atomicAdd(&G[b * ADIM + d], s);
}

// ---------------------------------------------------------------------------
// kg[n,d] = bf16( G_raw[b,d] * (1/max(||a||,eps)) * kn[n,d] )
// ---------------------------------------------------------------------------
__global__ __launch_bounds__(256) void kgk(
    const float* __restrict__ k, const float* __restrict__ G,
    const float* __restrict__ assq, bf16_t* __restrict__ kg)
{
    size_t i = (size_t)blockIdx.x * 256 + threadIdx.x;   // grid = M*ADIM/256
    int d = i & (ADIM - 1);
    size_t row = i >> 8;
    int b = (int)(row >> 12);
    float invn = 1.f / fmaxf(sqrtf(assq[b]), 1e-12f);
    kg[i] = __float2bfloat16(G[b * ADIM + d] * invn * k[i]);
}

// ---------------------------------------------------------------------------
// GEMM: C[M,N] = A[M,K] * BT[N,K]^T  (both bf16, fp32 accum, fp32 bias)
// EPI 0: out fp32 = acc + bias
// EPI 1: out bf16 = acc + bias + addsrc(fp32)
// EPI 2: out bf16 = gelu(acc + bias)          (exact, erf)
// EPI 3: resid fp32 += acc + bias
// Tile 128x128x32, 4 waves, 4x4 mfma_16x16x32_bf16 frags per wave.
// ---------------------------------------------------------------------------
#define BM 128
#define BN 128
#define BK 32
#define LDK 40   // padded LDS k-stride (bf16 elems); 80B keeps 16B alignment

template <int EPI>
__global__ __launch_bounds__(256, 2) void gemm_bt(
    const bf16_t* __restrict__ A, const bf16_t* __restrict__ BT,
    int M, int N, int K,
    const float* __restrict__ bias,
    const float* __restrict__ addsrc,
    float* __restrict__ resid,
    void* __restrict__ out)
{
    __shared__ unsigned short As[BM * LDK];
    __shared__ unsigned short Bs[BN * LDK];
    int tid = threadIdx.x;
    int lane = tid & 63, wid = tid >> 6;
    int wr = wid >> 1, wc = wid & 1;
    int m0 = blockIdx.y * BM, n0 = blockIdx.x * BN;

    f32x4 acc[4][4];
#pragma unroll
    for (int i = 0; i < 4; i++)
#pragma unroll
        for (int j = 0; j < 4; j++) acc[i][j] = f32x4{0.f, 0.f, 0.f, 0.f};

    int sr = tid >> 2;            // staging row (0..63), +64 for second half
    int sc = (tid & 3) * 8;       // staging col in bf16 elems
    const unsigned short* Ap = (const unsigned short*)A + (size_t)(m0 + sr) * K + sc;
    const unsigned short* Bp = (const unsigned short*)BT + (size_t)(n0 + sr) * K + sc;
    size_t rstep = (size_t)64 * K;

    int kq = (lane >> 4) * 8;     // k offset of this lane's fragment
    int mrow = lane & 15;

    for (int k0 = 0; k0 < K; k0 += BK) {
        uint4 a0 = *(const uint4*)(Ap + k0);
        uint4 a1 = *(const uint4*)(Ap + rstep + k0);
        uint4 b0 = *(const uint4*)(Bp + k0);
        uint4 b1 = *(const uint4*)(Bp + rstep + k0);
        __syncthreads();   // previous iter's LDS reads complete
        *(uint4*)&As[sr * LDK + sc] = a0;
        *(uint4*)&As[(sr + 64) * LDK + sc] = a1;
        *(uint4*)&Bs[sr * LDK + sc] = b0;
        *(uint4*)&Bs[(sr + 64) * LDK + sc] = b1;
        __syncthreads();
        bhalf8 af[4], bfrag[4];
#pragma unroll
        for (int i = 0; i < 4; i++)
            af[i] = *(const bhalf8*)&As[(wr * 64 + i * 16 + mrow) * LDK + kq];
#pragma unroll
        for (int j = 0; j < 4; j++)
            bfrag[j] = *(const bhalf8*)&Bs[(wc * 64 + j * 16 + mrow) * LDK + kq];
#pragma unroll
        for (int i = 0; i < 4; i++)
#pragma unroll
            for (int j = 0; j < 4; j++)
                acc[i][j] = __builtin_amdgcn_mfma_f32_16x16x32_bf16(
                    af[i], bfrag[j], acc[i][j], 0, 0, 0);
    }

    // epilogue: C/D layout col = lane&15, row = (lane>>4)*4 + reg
    int crow = wr * 64 + (lane >> 4) * 4;
    int ccol = wc * 64 + (lane & 15);
#pragma unroll
    for (int j = 0; j < 4; j++) {
        int col = n0 + ccol + j * 16;
        float bv = bias[col];
#pragma unroll
        for (int i = 0; i < 4; i++) {
#pragma unroll
            for (int r = 0; r < 4; r++) {
                int row = m0 + crow + i * 16 + r;
                size_t idx = (size_t)row * N + col;
                float v = acc[i][j][r] + bv;
                if (EPI == 0) {
                    ((float*)out)[idx] = v;
                } else if (EPI == 1) {
                    v += addsrc[idx];
                    ((bf16_t*)out)[idx] = __float2bfloat16(v);
                } else if (EPI == 2) {
                    float gl = 0.5f * v * (1.f + erff(v * 0.70710678118f));
                    ((bf16_t*)out)[idx] = __float2bfloat16(gl);
                } else {
                    resid[idx] += v;
                }
            }
        }
    }
}

// ---------------------------------------------------------------------------
extern "C" void kernel_launch(void* const* d_in, const int* in_sizes, int n_in,
                              void* d_out, int out_size, void* d_ws, size_t ws_size,
                              hipStream_t stream)
{
    // ALL inputs are float32 (reference dtypes). Output float32.
    const float* x_in  = (const float*)d_in[0];
    const float* ln1_g = (const float*)d_in[1];
    const float* ln1_b = (const float*)d_in[2];
    const float* Wq    = (const float*)d_in[3];
    const float* bq    = (const float*)d_in[4];
    const float* Wk    = (const float*)d_in[5];
    const float* bk    = (const float*)d_in[6];
    const float* wg    = (const float*)d_in[7];
    const float* Wp    = (const float*)d_in[8];
    const float* bp    = (const float*)d_in[9];
    const float* Wf    = (const float*)d_in[10];
    const float* bfv   = (const float*)d_in[11];
    const float* ln2_g = (const float*)d_in[12];
    const float* ln2_b = (const float*)d_in[13];
    const float* W1    = (const float*)d_in[14];
    const float* b1    = (const float*)d_in[15];
    const float* W2    = (const float*)d_in[16];
    const float* b2    = (const float*)d_in[17];

    char* w = (char*)d_ws;
    size_t off = 0;
    auto alloc = [&](size_t bytes) {
        off = (off + 255) & ~(size_t)255;
        void* p = w + off;
        off += bytes;
        return p;
    };

    // ws budget ~135 MiB (known-safe: 167 MiB fit in round 2)
    bf16_t* WqT = (bf16_t*)alloc((size_t)DEPTH * ADIM * DIM * 2);   //  2 MiB
    bf16_t* WkT = (bf16_t*)alloc((size_t)DEPTH * ADIM * DIM * 2);   //  2 MiB
    bf16_t* WpT = (bf16_t*)alloc((size_t)DEPTH * ADIM * ADIM * 2);  //  0.5 MiB
    bf16_t* WfT = (bf16_t*)alloc((size_t)DEPTH * DIM * ADIM * 2);   //  2 MiB
    bf16_t* W1T = (bf16_t*)alloc((size_t)HID * DIM * 2);            //  8 MiB (1 layer)
    bf16_t* W2T = (bf16_t*)alloc((size_t)DIM * HID * 2);            //  8 MiB (1 layer)
    float*  x   = (float*)alloc((size_t)MTOT * DIM * 4);            // 64 MiB
    float*  q   = (float*)alloc((size_t)MTOT * ADIM * 4);           // 16 MiB
    float*  k   = (float*)alloc((size_t)MTOT * ADIM * 4);           // 16 MiB
    float*  a   = (float*)alloc((size_t)MTOT * 4);                  // 64 KiB
    float*  assq = (float*)alloc((size_t)(4 + BATCH * ADIM) * 4);
    float*  G   = assq + 4;
    bf16_t* kg  = (bf16_t*)alloc((size_t)MTOT * ADIM * 2);          //  8 MiB
    bf16_t* ob  = (bf16_t*)alloc((size_t)MTOT * ADIM * 2);          //  8 MiB
    // d_out (64 MiB fp32) doubles as bf16 scratch until the final copy:
    bf16_t* h    = (bf16_t*)d_out;                    // 32 MiB: LN output
    bf16_t* hidc = (bf16_t*)d_out + (size_t)MTOT * DIM; // 32 MiB: MLP hidden chunk
    (void)ws_size; (void)in_sizes; (void)n_in; (void)out_size;

    // small weights -> transposed bf16 copies, all layers
    for (int i = 0; i < DEPTH; i++) {
        cast_transpose<<<dim3(ADIM / 32, DIM / 32), dim3(32, 8), 0, stream>>>(
            Wq + (size_t)i * DIM * ADIM, WqT + (size_t)i * ADIM * DIM, DIM, ADIM);
        cast_transpose<<<dim3(ADIM / 32, DIM / 32), dim3(32, 8), 0, stream>>>(
            Wk + (size_t)i * DIM * ADIM, WkT + (size_t)i * ADIM * DIM, DIM, ADIM);
        cast_transpose<<<dim3(ADIM / 32, ADIM / 32), dim3(32, 8), 0, stream>>>(
            Wp + (size_t)i * ADIM * ADIM, WpT + (size_t)i * ADIM * ADIM, ADIM, ADIM);
        cast_transpose<<<dim3(DIM / 32, ADIM / 32), dim3(32, 8), 0, stream>>>(
            Wf + (size_t)i * ADIM * DIM, WfT + (size_t)i * DIM * ADIM, ADIM, DIM);
    }

    // x (fp32 residual stream) <- x_in
    hipMemcpyAsync(x, x_in, (size_t)MTOT * DIM * 4, hipMemcpyDeviceToDevice, stream);

    for (int i = 0; i < DEPTH; i++) {
        ln_kernel<<<MTOT, 256, 0, stream>>>(x, ln1_g + i * DIM, ln1_b + i * DIM, h);
        gemm_bt<0><<<dim3(ADIM / BN, MTOT / BM), 256, 0, stream>>>(
            h, WqT + (size_t)i * ADIM * DIM, MTOT, ADIM, DIM,
            bq + i * ADIM, nullptr, nullptr, q);
        gemm_bt<0><<<dim3(ADIM / BN, MTOT / BM), 256, 0, stream>>>(
            h, WkT + (size_t)i * ADIM * DIM, MTOT, ADIM, DIM,
            bk + i * ADIM, nullptr, nullptr, k);
        hipMemsetAsync(assq, 0, (4 + BATCH * ADIM) * 4, stream);
        qknorm<<<MTOT / 4, 256, 0, stream>>>(q, k, wg + i * ADIM, a, assq);
        gacc<<<dim3(SEQ / 256, BATCH), 256, 0, stream>>>(q, a, G);
        kgk<<<MTOT * ADIM / 256, 256, 0, stream>>>(k, G, assq, kg);
        gemm_bt<1><<<dim3(ADIM / BN, MTOT / BM), 256, 0, stream>>>(
            kg, WpT + (size_t)i * ADIM * ADIM, MTOT, ADIM, ADIM,
            bp + i * ADIM, q, nullptr, ob);
        gemm_bt<3><<<dim3(DIM / BN, MTOT / BM), 256, 0, stream>>>(
            ob, WfT + (size_t)i * DIM * ADIM, MTOT, DIM, ADIM,
            bfv + i * DIM, nullptr, x, nullptr);
        ln_kernel<<<MTOT, 256, 0, stream>>>(x, ln2_g + i * DIM, ln2_b + i * DIM, h);

        // MLP: per-layer weight transpose + M-chunked hidden
        cast_transpose<<<dim3(HID / 32, DIM / 32), dim3(32, 8), 0, stream>>>(
            W1 + (size_t)i * DIM * HID, W1T, DIM, HID);
        cast_transpose<<<dim3(DIM / 32, HID / 32), dim3(32, 8), 0, stream>>>(
            W2 + (size_t)i * HID * DIM, W2T, HID, DIM);
        for (int c = 0; c < MTOT / MCHUNK; c++) {
            size_t r0 = (size_t)c * MCHUNK;
            gemm_bt<2><<<dim3(HID / BN, MCHUNK / BM), 256, 0, stream>>>(
                h + r0 * DIM, W1T, MCHUNK, HID, DIM,
                b1 + i * HID, nullptr, nullptr, hidc);
            gemm_bt<3><<<dim3(DIM / BN, MCHUNK / BM), 256, 0, stream>>>(
                hidc, W2T, MCHUNK, DIM, HID,
                b2 + i * DIM, nullptr, x + r0 * DIM, nullptr);
        }
    }

    // final: d_out (fp32) <- x
    hipMemcpyAsync(d_out, x, (size_t)MTOT * DIM * 4, hipMemcpyDeviceToDevice, stream);
}

// Round 4
// 3373.651 us; speedup vs baseline: 1.2325x; 1.2325x over previous
//
#include <hip/hip_runtime.h>
#include <hip/hip_bf16.h>
#include <math.h>

typedef __hip_bfloat16 bf16_t;
typedef __bf16 bhalf8 __attribute__((ext_vector_type(8)));
typedef float f32x4 __attribute__((ext_vector_type(4)));

#define DEPTH 4
#define DIM   1024
#define ADIM  256
#define HID   4096
#define BATCH 4
#define SEQ   4096
#define MTOT  (BATCH*SEQ)   // 16384 rows
#define MCHUNK 4096         // MLP hidden computed in 4 row-chunks

// ---------------------------------------------------------------------------
// cast+transpose: W [K][N] fp32 -> WT [N][K] bf16  (B^T rows for the GEMM)
// grid (N/32, K/32), block (32,8)
// ---------------------------------------------------------------------------
__global__ __launch_bounds__(256) void cast_transpose(
    const float* __restrict__ W, bf16_t* __restrict__ WT, int K, int N)
{
    __shared__ float t[32][33];
    unsigned short* WTl = (unsigned short*)WT;
    int n0 = blockIdx.x * 32, k0 = blockIdx.y * 32;
    int tx = threadIdx.x, ty = threadIdx.y;
#pragma unroll
    for (int i = 0; i < 4; i++)
        t[ty + i * 8][tx] = W[(size_t)(k0 + ty + i * 8) * N + n0 + tx];
    __syncthreads();
#pragma unroll
    for (int i = 0; i < 4; i++) {
        __hip_bfloat16 v = __float2bfloat16(t[tx][ty + i * 8]);
        WTl[(size_t)(n0 + ty + i * 8) * K + k0 + tx] = *(unsigned short*)&v;
    }
}

// ---------------------------------------------------------------------------
// LayerNorm: x fp32 [M,1024] -> h bf16 [M,1024]. One block / row.
// ---------------------------------------------------------------------------
__global__ __launch_bounds__(256) void ln_kernel(
    const float* __restrict__ x, const float* __restrict__ g,
    const float* __restrict__ b, bf16_t* __restrict__ h)
{
    int row = blockIdx.x;
    const float* xr = x + (size_t)row * DIM;
    int tid = threadIdx.x;
    float4 v = ((const float4*)xr)[tid];
    float s  = v.x + v.y + v.z + v.w;
    float ss = v.x * v.x + v.y * v.y + v.z * v.z + v.w * v.w;
#pragma unroll
    for (int off = 32; off > 0; off >>= 1) {
        s  += __shfl_down(s, off, 64);
        ss += __shfl_down(ss, off, 64);
    }
    __shared__ float sbuf[8];
    int wid = tid >> 6, lane = tid & 63;
    if (lane == 0) { sbuf[wid] = s; sbuf[4 + wid] = ss; }
    __syncthreads();
    if (tid == 0) {
        float S  = sbuf[0] + sbuf[1] + sbuf[2] + sbuf[3];
        float SS = sbuf[4] + sbuf[5] + sbuf[6] + sbuf[7];
        float mu  = S * (1.f / DIM);
        float var = SS * (1.f / DIM) - mu * mu;
        sbuf[0] = mu;
        sbuf[1] = rsqrtf(var + 1e-6f);
    }
    __syncthreads();
    float mu = sbuf[0], rs = sbuf[1];
    bf16_t* hr = h + (size_t)row * DIM;
    int c = tid * 4;
    float4 gv = ((const float4*)g)[tid];
    float4 bv = ((const float4*)b)[tid];
    hr[c + 0] = __float2bfloat16((v.x - mu) * rs * gv.x + bv.x);
    hr[c + 1] = __float2bfloat16((v.y - mu) * rs * gv.y + bv.y);
    hr[c + 2] = __float2bfloat16((v.z - mu) * rs * gv.z + bv.z);
    hr[c + 3] = __float2bfloat16((v.w - mu) * rs * gv.w + bv.w);
}

// ---------------------------------------------------------------------------
// q/k l2-normalize (in-place fp32) + a[row] = (qn . w_g)*SCALE
// block = 256 (4 waves, one row per wave), grid = M/4.  NO atomics.
// ---------------------------------------------------------------------------
__global__ __launch_bounds__(256) void qknorm(
    float* __restrict__ q, float* __restrict__ k,
    const float* __restrict__ wg, float* __restrict__ a)
{
    int wid = threadIdx.x >> 6, lane = threadIdx.x & 63;
    int row = blockIdx.x * 4 + wid;
    float4* qr = (float4*)(q + (size_t)row * ADIM);
    float4* kr = (float4*)(k + (size_t)row * ADIM);
    float4 qv = qr[lane], kv = kr[lane];
    float qss = qv.x * qv.x + qv.y * qv.y + qv.z * qv.z + qv.w * qv.w;
    float kss = kv.x * kv.x + kv.y * kv.y + kv.z * kv.z + kv.w * kv.w;
#pragma unroll
    for (int off = 32; off > 0; off >>= 1) {
        qss += __shfl_down(qss, off, 64);
        kss += __shfl_down(kss, off, 64);
    }
    qss = __shfl(qss, 0, 64);
    kss = __shfl(kss, 0, 64);
    float qi = 1.f / fmaxf(sqrtf(qss), 1e-12f);
    float ki = 1.f / fmaxf(sqrtf(kss), 1e-12f);
    qv.x *= qi; qv.y *= qi; qv.z *= qi; qv.w *= qi;
    kv.x *= ki; kv.y *= ki; kv.z *= ki; kv.w *= ki;
    qr[lane] = qv;
    kr[lane] = kv;
    // a = dot(qn, w_g) * SCALE
    float4 wgv = ((const float4*)wg)[lane];
    float ad = qv.x * wgv.x + qv.y * wgv.y + qv.z * wgv.z + qv.w * wgv.w;
#pragma unroll
    for (int off = 32; off > 0; off >>= 1) ad += __shfl_down(ad, off, 64);
    if (lane == 0) a[row] = ad * 0.25f;   // SCALE = 16^-0.5
}

// ---------------------------------------------------------------------------
// assq[b] = sum_n a[b,n]^2.  One block per batch, tree reduction, no atomics.
// ---------------------------------------------------------------------------
__global__ __launch_bounds__(256) void anorm(
    const float* __restrict__ a, float* __restrict__ assq)
{
    int b = blockIdx.x, tid = threadIdx.x;
    const float* ab = a + (size_t)b * SEQ;
    float s = 0.f;
    for (int i = tid; i < SEQ; i += 256) { float v = ab[i]; s += v * v; }
#pragma unroll
    for (int off = 32; off > 0; off >>= 1) s += __shfl_down(s, off, 64);
    __shared__ float sbuf[4];
    if ((tid & 63) == 0) sbuf[tid >> 6] = s;
    __syncthreads();
    if (tid == 0) assq[b] = sbuf[0] + sbuf[1] + sbuf[2] + sbuf[3];
}

// ---------------------------------------------------------------------------
// G_raw[b][d] = sum_n a[b,n] * qn[b,n,d]   (atomic accumulate, G pre-zeroed)
// grid (16 chunks, 4 batches), block 256 (d)
// ---------------------------------------------------------------------------
__global__ __launch_bounds__(256) void gacc(
    const float* __restrict__ q, const float* __restrict__ a,
    float* __restrict__ G)
{
    int b = blockIdx.y, chunk = blockIdx.x, d = threadIdx.x;
    const float* qb = q + ((size_t)b * SEQ + chunk * 256) * ADIM;
    const float* ab = a + (size_t)b * SEQ + chunk * 256;
    float s = 0.f;
    for (int n = 0; n < 256; n++) s += ab[n] * qb[(size_t)n * ADIM + d];
    atomicAdd(&G[b * ADIM + d], s);
}

// ---------------------------------------------------------------------------
// kg[n,d] = bf16( G_raw[b,d] * (1/max(||a||,eps)) * kn[n,d] )
// ---------------------------------------------------------------------------
__global__ __launch_bounds__(256) void kgk(
    const float* __restrict__ k, const float* __restrict__ G,
    const float* __restrict__ assq, bf16_t* __restrict__ kg)
{
    size_t i = (size_t)blockIdx.x * 256 + threadIdx.x;   // grid = M*ADIM/256
    int d = i & (ADIM - 1);
    size_t row = i >> 8;
    int b = (int)(row >> 12);
    float invn = 1.f / fmaxf(sqrtf(assq[b]), 1e-12f);
    kg[i] = __float2bfloat16(G[b * ADIM + d] * invn * k[i]);
}

// ---------------------------------------------------------------------------
// GEMM: C[M,N] = A[M,K] * BT[N,K]^T  (both bf16, fp32 accum, fp32 bias)
// EPI 0: out fp32 = acc + bias
// EPI 1: out bf16 = acc + bias + addsrc(fp32)
// EPI 2: out bf16 = gelu(acc + bias)          (exact, erf)
// EPI 3: resid fp32 += acc + bias
// Tile 128x128x32, 4 waves, 4x4 mfma_16x16x32_bf16 frags per wave.
// ---------------------------------------------------------------------------
#define BM 128
#define BN 128
#define BK 32
#define LDK 40   // padded LDS k-stride (bf16 elems); 80B keeps 16B alignment

template <int EPI>
__global__ __launch_bounds__(256, 2) void gemm_bt(
    const bf16_t* __restrict__ A, const bf16_t* __restrict__ BT,
    int M, int N, int K,
    const float* __restrict__ bias,
    const float* __restrict__ addsrc,
    float* __restrict__ resid,
    void* __restrict__ out)
{
    __shared__ unsigned short As[BM * LDK];
    __shared__ unsigned short Bs[BN * LDK];
    int tid = threadIdx.x;
    int lane = tid & 63, wid = tid >> 6;
    int wr = wid >> 1, wc = wid & 1;
    int m0 = blockIdx.y * BM, n0 = blockIdx.x * BN;

    f32x4 acc[4][4];
#pragma unroll
    for (int i = 0; i < 4; i++)
#pragma unroll
        for (int j = 0; j < 4; j++) acc[i][j] = f32x4{0.f, 0.f, 0.f, 0.f};

    int sr = tid >> 2;            // staging row (0..63), +64 for second half
    int sc = (tid & 3) * 8;       // staging col in bf16 elems
    const unsigned short* Ap = (const unsigned short*)A + (size_t)(m0 + sr) * K + sc;
    const unsigned short* Bp = (const unsigned short*)BT + (size_t)(n0 + sr) * K + sc;
    size_t rstep = (size_t)64 * K;

    int kq = (lane >> 4) * 8;     // k offset of this lane's fragment
    int mrow = lane & 15;

    for (int k0 = 0; k0 < K; k0 += BK) {
        uint4 a0 = *(const uint4*)(Ap + k0);
        uint4 a1 = *(const uint4*)(Ap + rstep + k0);
        uint4 b0 = *(const uint4*)(Bp + k0);
        uint4 b1 = *(const uint4*)(Bp + rstep + k0);
        __syncthreads();   // previous iter's LDS reads complete
        *(uint4*)&As[sr * LDK + sc] = a0;
        *(uint4*)&As[(sr + 64) * LDK + sc] = a1;
        *(uint4*)&Bs[sr * LDK + sc] = b0;
        *(uint4*)&Bs[(sr + 64) * LDK + sc] = b1;
        __syncthreads();
        bhalf8 af[4], bfrag[4];
#pragma unroll
        for (int i = 0; i < 4; i++)
            af[i] = *(const bhalf8*)&As[(wr * 64 + i * 16 + mrow) * LDK + kq];
#pragma unroll
        for (int j = 0; j < 4; j++)
            bfrag[j] = *(const bhalf8*)&Bs[(wc * 64 + j * 16 + mrow) * LDK + kq];
#pragma unroll
        for (int i = 0; i < 4; i++)
#pragma unroll
            for (int j = 0; j < 4; j++)
                acc[i][j] = __builtin_amdgcn_mfma_f32_16x16x32_bf16(
                    af[i], bfrag[j], acc[i][j], 0, 0, 0);
    }

    // epilogue: C/D layout col = lane&15, row = (lane>>4)*4 + reg
    int crow = wr * 64 + (lane >> 4) * 4;
    int ccol = wc * 64 + (lane & 15);
#pragma unroll
    for (int j = 0; j < 4; j++) {
        int col = n0 + ccol + j * 16;
        float bv = bias[col];
#pragma unroll
        for (int i = 0; i < 4; i++) {
#pragma unroll
            for (int r = 0; r < 4; r++) {
                int row = m0 + crow + i * 16 + r;
                size_t idx = (size_t)row * N + col;
                float v = acc[i][j][r] + bv;
                if (EPI == 0) {
                    ((float*)out)[idx] = v;
                } else if (EPI == 1) {
                    v += addsrc[idx];
                    ((bf16_t*)out)[idx] = __float2bfloat16(v);
                } else if (EPI == 2) {
                    float gl = 0.5f * v * (1.f + erff(v * 0.70710678118f));
                    ((bf16_t*)out)[idx] = __float2bfloat16(gl);
                } else {
                    resid[idx] += v;
                }
            }
        }
    }
}

// ---------------------------------------------------------------------------
extern "C" void kernel_launch(void* const* d_in, const int* in_sizes, int n_in,
                              void* d_out, int out_size, void* d_ws, size_t ws_size,
                              hipStream_t stream)
{
    // ALL inputs are float32 (reference dtypes). Output float32.
    const float* x_in  = (const float*)d_in[0];
    const float* ln1_g = (const float*)d_in[1];
    const float* ln1_b = (const float*)d_in[2];
    const float* Wq    = (const float*)d_in[3];
    const float* bq    = (const float*)d_in[4];
    const float* Wk    = (const float*)d_in[5];
    const float* bk    = (const float*)d_in[6];
    const float* wg    = (const float*)d_in[7];
    const float* Wp    = (const float*)d_in[8];
    const float* bp    = (const float*)d_in[9];
    const float* Wf    = (const float*)d_in[10];
    const float* bfv   = (const float*)d_in[11];
    const float* ln2_g = (const float*)d_in[12];
    const float* ln2_b = (const float*)d_in[13];
    const float* W1    = (const float*)d_in[14];
    const float* b1    = (const float*)d_in[15];
    const float* W2    = (const float*)d_in[16];
    const float* b2    = (const float*)d_in[17];

    char* w = (char*)d_ws;
    size_t off = 0;
    auto alloc = [&](size_t bytes) {
        off = (off + 255) & ~(size_t)255;
        void* p = w + off;
        off += bytes;
        return p;
    };

    // ws budget ~135 MiB (known-safe: 167 MiB fit in round 2)
    bf16_t* WqT = (bf16_t*)alloc((size_t)DEPTH * ADIM * DIM * 2);   //  2 MiB
    bf16_t* WkT = (bf16_t*)alloc((size_t)DEPTH * ADIM * DIM * 2);   //  2 MiB
    bf16_t* WpT = (bf16_t*)alloc((size_t)DEPTH * ADIM * ADIM * 2);  //  0.5 MiB
    bf16_t* WfT = (bf16_t*)alloc((size_t)DEPTH * DIM * ADIM * 2);   //  2 MiB
    bf16_t* W1T = (bf16_t*)alloc((size_t)HID * DIM * 2);            //  8 MiB (1 layer)
    bf16_t* W2T = (bf16_t*)alloc((size_t)DIM * HID * 2);            //  8 MiB (1 layer)
    float*  x   = (float*)alloc((size_t)MTOT * DIM * 4);            // 64 MiB
    float*  q   = (float*)alloc((size_t)MTOT * ADIM * 4);           // 16 MiB
    float*  k   = (float*)alloc((size_t)MTOT * ADIM * 4);           // 16 MiB
    float*  a   = (float*)alloc((size_t)MTOT * 4);                  // 64 KiB
    float*  assq = (float*)alloc((size_t)(4 + BATCH * ADIM) * 4);
    float*  G   = assq + 4;
    bf16_t* kg  = (bf16_t*)alloc((size_t)MTOT * ADIM * 2);          //  8 MiB
    bf16_t* ob  = (bf16_t*)alloc((size_t)MTOT * ADIM * 2);          //  8 MiB
    // d_out (64 MiB fp32) doubles as bf16 scratch until the final copy:
    bf16_t* h    = (bf16_t*)d_out;                    // 32 MiB: LN output
    bf16_t* hidc = (bf16_t*)d_out + (size_t)MTOT * DIM; // 32 MiB: MLP hidden chunk
    (void)ws_size; (void)in_sizes; (void)n_in; (void)out_size;

    // small weights -> transposed bf16 copies, all layers
    for (int i = 0; i < DEPTH; i++) {
        cast_transpose<<<dim3(ADIM / 32, DIM / 32), dim3(32, 8), 0, stream>>>(
            Wq + (size_t)i * DIM * ADIM, WqT + (size_t)i * ADIM * DIM, DIM, ADIM);
        cast_transpose<<<dim3(ADIM / 32, DIM / 32), dim3(32, 8), 0, stream>>>(
            Wk + (size_t)i * DIM * ADIM, WkT + (size_t)i * ADIM * DIM, DIM, ADIM);
        cast_transpose<<<dim3(ADIM / 32, ADIM / 32), dim3(32, 8), 0, stream>>>(
            Wp + (size_t)i * ADIM * ADIM, WpT + (size_t)i * ADIM * ADIM, ADIM, ADIM);
        cast_transpose<<<dim3(DIM / 32, ADIM / 32), dim3(32, 8), 0, stream>>>(
            Wf + (size_t)i * ADIM * DIM, WfT + (size_t)i * DIM * ADIM, ADIM, DIM);
    }

    // x (fp32 residual stream) <- x_in
    hipMemcpyAsync(x, x_in, (size_t)MTOT * DIM * 4, hipMemcpyDeviceToDevice, stream);

    for (int i = 0; i < DEPTH; i++) {
        ln_kernel<<<MTOT, 256, 0, stream>>>(x, ln1_g + i * DIM, ln1_b + i * DIM, h);
        gemm_bt<0><<<dim3(ADIM / BN, MTOT / BM), 256, 0, stream>>>(
            h, WqT + (size_t)i * ADIM * DIM, MTOT, ADIM, DIM,
            bq + i * ADIM, nullptr, nullptr, q);
        gemm_bt<0><<<dim3(ADIM / BN, MTOT / BM), 256, 0, stream>>>(
            h, WkT + (size_t)i * ADIM * DIM, MTOT, ADIM, DIM,
            bk + i * ADIM, nullptr, nullptr, k);
        qknorm<<<MTOT / 4, 256, 0, stream>>>(q, k, wg + i * ADIM, a);
        anorm<<<BATCH, 256, 0, stream>>>(a, assq);
        hipMemsetAsync(G, 0, (size_t)BATCH * ADIM * 4, stream);
        gacc<<<dim3(SEQ / 256, BATCH), 256, 0, stream>>>(q, a, G);
        kgk<<<MTOT * ADIM / 256, 256, 0, stream>>>(k, G, assq, kg);
        gemm_bt<1><<<dim3(ADIM / BN, MTOT / BM), 256, 0, stream>>>(
            kg, WpT + (size_t)i * ADIM * ADIM, MTOT, ADIM, ADIM,
            bp + i * ADIM, q, nullptr, ob);
        gemm_bt<3><<<dim3(DIM / BN, MTOT / BM), 256, 0, stream>>>(
            ob, WfT + (size_t)i * DIM * ADIM, MTOT, DIM, ADIM,
            bfv + i * DIM, nullptr, x, nullptr);
        ln_kernel<<<MTOT, 256, 0, stream>>>(x, ln2_g + i * DIM, ln2_b + i * DIM, h);

        // MLP: per-layer weight transpose + M-chunked hidden
        cast_transpose<<<dim3(HID / 32, DIM / 32), dim3(32, 8), 0, stream>>>(
            W1 + (size_t)i * DIM * HID, W1T, DIM, HID);
        cast_transpose<<<dim3(DIM / 32, HID / 32), dim3(32, 8), 0, stream>>>(
            W2 + (size_t)i * HID * DIM, W2T, HID, DIM);
        for (int c = 0; c < MTOT / MCHUNK; c++) {
            size_t r0 = (size_t)c * MCHUNK;
            gemm_bt<2><<<dim3(HID / BN, MCHUNK / BM), 256, 0, stream>>>(
                h + r0 * DIM, W1T, MCHUNK, HID, DIM,
                b1 + i * HID, nullptr, nullptr, hidc);
            gemm_bt<3><<<dim3(DIM / BN, MCHUNK / BM), 256, 0, stream>>>(
                hidc, W2T, MCHUNK, DIM, HID,
                b2 + i * DIM, nullptr, x + r0 * DIM, nullptr);
        }
    }

    // final: d_out (fp32) <- x
    hipMemcpyAsync(d_out, x, (size_t)MTOT * DIM * 4, hipMemcpyDeviceToDevice, stream);
}